// Round 1
// baseline (608.786 us; speedup 1.0000x reference)
//
#include <hip/hip_runtime.h>

// out[b,t,h] = sum_{m<7} images[b,t,m] * A[m,h]
// images: (64,576,7) fp32   A: (4096,4096) fp32 (only first 7 rows used)
// out:    (64,576,4096) fp32  -- 604 MB, pure HBM-write-bound stream.

typedef float f4 __attribute__((ext_vector_type(4)));

#define NROWS (64 * 576)   // 36864 (b,t) rows
#define HID   4096
#define MM    7
#define RPB   8            // rows per block: amortizes A loads 8x (keeps A traffic in L2)

__global__ __launch_bounds__(256) void vt_kernel(const float* __restrict__ images,
                                                 const float* __restrict__ A,
                                                 float* __restrict__ out) {
    const int row0 = blockIdx.x * RPB;

    // 8 rows x 7 coeffs at a wave-uniform contiguous address -> scalar loads.
    float x[RPB][MM];
#pragma unroll
    for (int r = 0; r < RPB; ++r) {
#pragma unroll
        for (int m = 0; m < MM; ++m) {
            x[r][m] = images[(size_t)(row0 + r) * MM + m];
        }
    }

    // 256 threads x float4 = 1024 cols/iter; 4 iters cover HID=4096.
#pragma unroll
    for (int it = 0; it < 4; ++it) {
        const int h = (threadIdx.x << 2) + (it << 10);

        f4 a[MM];
#pragma unroll
        for (int m = 0; m < MM; ++m) {
            a[m] = *(const f4*)(A + (size_t)m * HID + h);   // 114 KB slice, L2-resident
        }

#pragma unroll
        for (int r = 0; r < RPB; ++r) {
            f4 acc = x[r][0] * a[0];
#pragma unroll
            for (int m = 1; m < MM; ++m) {
                acc += x[r][m] * a[m];
            }
            // Write-once 604 MB stream: nt store, skip L2/L3 pollution.
            __builtin_nontemporal_store(acc, (f4*)(out + (size_t)(row0 + r) * HID + h));
        }
    }
}

extern "C" void kernel_launch(void* const* d_in, const int* in_sizes, int n_in,
                              void* d_out, int out_size, void* d_ws, size_t ws_size,
                              hipStream_t stream) {
    const float* images = (const float*)d_in[0];
    const float* A      = (const float*)d_in[1];
    float* out          = (float*)d_out;

    const int nblocks = NROWS / RPB;   // 4608 blocks -> 18 blocks/CU
    vt_kernel<<<nblocks, 256, 0, stream>>>(images, A, out);
}